// Round 7
// baseline (621.722 us; speedup 1.0000x reference)
//
#include <hip/hip_runtime.h>
#include <cmath>

#define BB 8
#define LL 512
#define DD 1024
#define HH 16
#define HDD 64
#define FFD 4096
#define MTOK (BB*LL)
#define EPSF 1e-5f
#define BK 64

typedef __attribute__((ext_vector_type(8))) short bf16x8;
typedef __attribute__((ext_vector_type(4))) float f32x4;

// scal slots: 0..5 weight absmax (q,k,v,o,fc,pj)
// 6,7 q obs | 8,9 k | 10,11 v | 18 maxp | 19,20 o | 21,22 fc | 23,24 pj

struct WSet {
  const float* w[6];
  unsigned short* q[6];
  int n4[6];
};

__device__ inline void atomicMaxPos(float* addr, float v) {
  atomicMax((unsigned int*)addr, __float_as_uint(v));  // v >= 0, slot init 0
}

__device__ inline unsigned short f2bf(float x) {  // RNE to bf16 bits
  unsigned int u = __float_as_uint(x);
  u += 0x7fffu + ((u >> 16) & 1u);
  return (unsigned short)(u >> 16);
}
__device__ inline float bf2f(unsigned short h) {
  return __uint_as_float((unsigned int)h << 16);
}

// async 16B global->LDS; dest addresses are base+lane*16 by construction
__device__ __forceinline__ void gld16(const unsigned short* g, unsigned short* l) {
  __builtin_amdgcn_global_load_lds(
      (const __attribute__((address_space(1))) unsigned int*)g,
      (__attribute__((address_space(3))) unsigned int*)l, 16, 0, 0);
}

__global__ void k_init_bcat(float* __restrict__ s, const float* __restrict__ b0,
                            const float* __restrict__ b1, const float* __restrict__ b2,
                            float* __restrict__ dst) {
  int i = blockIdx.x * blockDim.x + threadIdx.x;
  if (i < 256) s[i] = 0.0f;
  if (i < 3072) dst[i] = i < 1024 ? b0[i] : (i < 2048 ? b1[i - 1024] : b2[i - 2048]);
}

__global__ void k_absmax6(WSet ws, float* __restrict__ scal) {
  const int id = blockIdx.y;
  const float4* w4 = (const float4*)ws.w[id];
  const int n4 = ws.n4[id];
  float m = 0.0f;
  for (int i = blockIdx.x * blockDim.x + threadIdx.x; i < n4; i += gridDim.x * blockDim.x) {
    float4 v = w4[i];
    m = fmaxf(m, fmaxf(fmaxf(fabsf(v.x), fabsf(v.y)), fmaxf(fabsf(v.z), fabsf(v.w))));
  }
  #pragma unroll
  for (int o = 32; o; o >>= 1) m = fmaxf(m, __shfl_down(m, o, 64));
  __shared__ float sb[4];
  int lane = threadIdx.x & 63, wid = threadIdx.x >> 6;
  if (lane == 0) sb[wid] = m;
  __syncthreads();
  if (threadIdx.x == 0) atomicMaxPos(scal + id, fmaxf(fmaxf(sb[0], sb[1]), fmaxf(sb[2], sb[3])));
}

__global__ void k_quantw6(WSet ws, const float* __restrict__ scal) {
  const int id = blockIdx.y;
  float s = fmaxf(scal[id] / 127.0f, 1e-8f);
  const float4* w4 = (const float4*)ws.w[id];
  ushort4* q4 = (ushort4*)ws.q[id];
  const int n4 = ws.n4[id];
  for (int i = blockIdx.x * blockDim.x + threadIdx.x; i < n4; i += gridDim.x * blockDim.x) {
    float4 v = w4[i];
    ushort4 o;
    o.x = f2bf(fminf(fmaxf(rintf(v.x / s), -128.0f), 127.0f));
    o.y = f2bf(fminf(fmaxf(rintf(v.y / s), -128.0f), 127.0f));
    o.z = f2bf(fminf(fmaxf(rintf(v.z / s), -128.0f), 127.0f));
    o.w = f2bf(fminf(fmaxf(rintf(v.w / s), -128.0f), 127.0f));
    q4[i] = o;
  }
}

__device__ inline float2 fq_params(const float* sHi, const float* sNeg) {
  float hi = *sHi, lo = -(*sNeg);
  float scale = fmaxf((hi - lo) / 255.0f, 1e-8f);
  float zp = rintf(-lo / scale);
  return make_float2(scale, zp);
}
__device__ inline float fq1(float x, float scale, float zp) {
  float q = fminf(fmaxf(rintf(x / scale) + zp, 0.0f), 255.0f);
  return (q - zp) * scale;
}
__device__ inline float2 fq_params2(const float* sHi, const float* sNeg) {
  float2 p1 = fq_params(sHi, sNeg);
  float hi2 = fq1(*sHi, p1.x, p1.y);
  float lo2 = fq1(-(*sNeg), p1.x, p1.y);
  float scale = fmaxf((hi2 - lo2) / 255.0f, 1e-8f);
  float zp = rintf(-lo2 / scale);
  return make_float2(scale, zp);
}
__device__ inline float code2(float x, float2 p1, float2 p2) {
  float v1 = fq1(x, p1.x, p1.y);
  float q = fminf(fmaxf(rintf(v1 / p2.x) + p2.y, 0.0f), 255.0f);
  return q - p2.y;
}

// raw qkv (ld 3072) -> double-fq -> bf16 integer codes packed [4096][1024]
__global__ void k_quant_codes(const float* __restrict__ src, int colBase,
                              unsigned short* __restrict__ oc, const float* __restrict__ sl) {
  float2 p1 = fq_params(sl, sl + 1);
  float2 p2 = fq_params2(sl, sl + 1);
  const int n4 = MTOK * DD / 4;
  for (int i = blockIdx.x * blockDim.x + threadIdx.x; i < n4; i += gridDim.x * blockDim.x) {
    int row = i >> 8, c = (i & 255) * 4;
    float4 v = *(const float4*)(src + (size_t)row * 3072 + colBase + c);
    ushort4 o;
    o.x = f2bf(code2(v.x, p1, p2)); o.y = f2bf(code2(v.y, p1, p2));
    o.z = f2bf(code2(v.z, p1, p2)); o.w = f2bf(code2(v.w, p1, p2));
    *(ushort4*)&oc[(size_t)row * DD + c] = o;
  }
}

// V codes per-head transposed: vt[((b*H+h)*64+d)*512 + m]; src ld 3072, col base 2048
__global__ __launch_bounds__(256) void k_quant_codes_vt(
    const float* __restrict__ src, unsigned short* __restrict__ vt,
    const float* __restrict__ sl) {
  __shared__ unsigned short tile[64 * 68];
  float2 p1 = fq_params(sl, sl + 1);
  float2 p2 = fq_params2(sl, sl + 1);
  const int m0 = blockIdx.x * 64, h = blockIdx.y, b = blockIdx.z;
  const int t = threadIdx.x;
  const int r = t >> 2, c0 = (t & 3) * 16;
  const float* s4 = src + ((size_t)(b * LL + m0 + r)) * 3072 + 2048 + h * HDD + c0;
  #pragma unroll
  for (int i = 0; i < 4; ++i) {
    float4 v = *(const float4*)(s4 + i * 4);
    ushort4 o;
    o.x = f2bf(code2(v.x, p1, p2)); o.y = f2bf(code2(v.y, p1, p2));
    o.z = f2bf(code2(v.z, p1, p2)); o.w = f2bf(code2(v.w, p1, p2));
    *(ushort4*)&tile[r * 68 + c0 + i * 4] = o;
  }
  __syncthreads();
  const int dr = t >> 2, ms = (t & 3) * 16;
  unsigned short* dst = vt + ((size_t)((b * HH + h) * HDD + dr)) * LL + m0 + ms;
  #pragma unroll
  for (int i = 0; i < 4; ++i) {
    ushort4 o;
    o.x = tile[(ms + i * 4 + 0) * 68 + dr];
    o.y = tile[(ms + i * 4 + 1) * 68 + dr];
    o.z = tile[(ms + i * 4 + 2) * 68 + dr];
    o.w = tile[(ms + i * 4 + 3) * 68 + dr];
    *(ushort4*)(dst + i * 4) = o;
  }
}

// lin = sum(parts) + bias -> minmax observer
__global__ void k_sum_minmax(const float* __restrict__ parts, size_t pstride4, int np,
                             const float* __restrict__ bias, int n4, int cmask,
                             float* __restrict__ sl) {
  float hi = 0.0f, ng = 0.0f;
  for (int i = blockIdx.x * blockDim.x + threadIdx.x; i < n4; i += gridDim.x * blockDim.x) {
    float4 bc = *(const float4*)(bias + (i & cmask) * 4);
    float vx = bc.x, vy = bc.y, vz = bc.z, vw = bc.w;
    for (int j = 0; j < np; ++j) {
      float4 a = ((const float4*)parts)[j * pstride4 + i];
      vx += a.x; vy += a.y; vz += a.z; vw += a.w;
    }
    hi = fmaxf(hi, fmaxf(fmaxf(vx, vy), fmaxf(vz, vw)));
    ng = fmaxf(ng, fmaxf(fmaxf(-vx, -vy), fmaxf(-vz, -vw)));
  }
  #pragma unroll
  for (int o = 32; o; o >>= 1) {
    hi = fmaxf(hi, __shfl_down(hi, o, 64));
    ng = fmaxf(ng, __shfl_down(ng, o, 64));
  }
  __shared__ float sh[4], sn[4];
  int lane = threadIdx.x & 63, wid = threadIdx.x >> 6;
  if (lane == 0) { sh[wid] = hi; sn[wid] = ng; }
  __syncthreads();
  if (threadIdx.x == 0) {
    atomicMaxPos(sl, fmaxf(fmaxf(sh[0], sh[1]), fmaxf(sh[2], sh[3])));
    atomicMaxPos(sl + 1, fmaxf(fmaxf(sn[0], sn[1]), fmaxf(sn[2], sn[3])));
  }
}

// out = res + fq(sum(parts)+bias)
__global__ void k_quant_res2(const float* __restrict__ parts, size_t pstride4, int np,
                             const float* __restrict__ bias, const float* __restrict__ res,
                             float* __restrict__ out, int n4, int cmask,
                             const float* __restrict__ sl) {
  float2 p = fq_params(sl, sl + 1);
  for (int i = blockIdx.x * blockDim.x + threadIdx.x; i < n4; i += gridDim.x * blockDim.x) {
    float4 bc = *(const float4*)(bias + (i & cmask) * 4);
    float vx = bc.x, vy = bc.y, vz = bc.z, vw = bc.w;
    for (int j = 0; j < np; ++j) {
      float4 a = ((const float4*)parts)[j * pstride4 + i];
      vx += a.x; vy += a.y; vz += a.z; vw += a.w;
    }
    float4 r = ((const float4*)res)[i];
    float4 o;
    o.x = r.x + fq1(vx, p.x, p.y);
    o.y = r.y + fq1(vy, p.x, p.y);
    o.z = r.z + fq1(vz, p.x, p.y);
    o.w = r.w + fq1(vw, p.x, p.y);
    ((float4*)out)[i] = o;
  }
}

__device__ inline float gelu_exact(float g) {
  return 0.5f * g * (1.0f + erff(g * 0.7071067811865475f));
}

// fc raw -> gelu(fq(.)) -> bf16 hi/lo
__global__ void k_gelu_codes(const float* __restrict__ x,
                             unsigned short* __restrict__ ghi, unsigned short* __restrict__ glo,
                             int n4, const float* __restrict__ sl) {
  float2 p = fq_params(sl, sl + 1);
  for (int i = blockIdx.x * blockDim.x + threadIdx.x; i < n4; i += gridDim.x * blockDim.x) {
    float4 v = ((const float4*)x)[i];
    float g0 = gelu_exact(fq1(v.x, p.x, p.y)), g1 = gelu_exact(fq1(v.y, p.x, p.y));
    float g2 = gelu_exact(fq1(v.z, p.x, p.y)), g3 = gelu_exact(fq1(v.w, p.x, p.y));
    ushort4 h, l;
    h.x = f2bf(g0); l.x = f2bf(g0 - bf2f(h.x));
    h.y = f2bf(g1); l.y = f2bf(g1 - bf2f(h.y));
    h.z = f2bf(g2); l.z = f2bf(g2 - bf2f(h.z));
    h.w = f2bf(g3); l.w = f2bf(g3 - bf2f(h.w));
    ((ushort4*)ghi)[i] = h;
    ((ushort4*)glo)[i] = l;
  }
}

__device__ inline float block_sum256(float v, float* sb) {
  #pragma unroll
  for (int o = 32; o; o >>= 1) v += __shfl_down(v, o, 64);
  int lane = threadIdx.x & 63, wid = threadIdx.x >> 6;
  __syncthreads();
  if (lane == 0) sb[wid] = v;
  __syncthreads();
  return sb[0] + sb[1] + sb[2] + sb[3];
}

// LayerNorm -> bf16 hi/lo pair
__global__ __launch_bounds__(256) void k_ln_bf(const float* __restrict__ x, const float* __restrict__ g,
                                               const float* __restrict__ bta,
                                               unsigned short* __restrict__ ohi,
                                               unsigned short* __restrict__ olo) {
  __shared__ float sb[4];
  int row = blockIdx.x;
  const float4* xr = (const float4*)(x + (size_t)row * DD);
  float4 v = xr[threadIdx.x];
  float mu = block_sum256(v.x + v.y + v.z + v.w, sb) * (1.0f / DD);
  float dx = v.x - mu, dy = v.y - mu, dz = v.z - mu, dw = v.w - mu;
  float var = block_sum256(dx*dx + dy*dy + dz*dz + dw*dw, sb) * (1.0f / DD);
  float rs = 1.0f / sqrtf(var + EPSF);
  float4 gv = ((const float4*)g)[threadIdx.x];
  float4 bv = ((const float4*)bta)[threadIdx.x];
  float o0 = dx * rs * gv.x + bv.x;
  float o1 = dy * rs * gv.y + bv.y;
  float o2 = dz * rs * gv.z + bv.z;
  float o3 = dw * rs * gv.w + bv.w;
  ushort4 h, l;
  h.x = f2bf(o0); l.x = f2bf(o0 - bf2f(h.x));
  h.y = f2bf(o1); l.y = f2bf(o1 - bf2f(h.y));
  h.z = f2bf(o2); l.z = f2bf(o2 - bf2f(h.z));
  h.w = f2bf(o3); l.w = f2bf(o3 - bf2f(h.w));
  ((ushort4*)(ohi + (size_t)row * DD))[threadIdx.x] = h;
  ((ushort4*)(olo + (size_t)row * DD))[threadIdx.x] = l;
}

// fused: x1 = res + fq(p0+p1+bias), then LayerNorm(x1) -> bf16 hi/lo (one block per row)
__global__ __launch_bounds__(256) void k_res_ln(
    const float* __restrict__ parts, size_t pstride4,
    const float* __restrict__ bias, const float* __restrict__ res,
    float* __restrict__ x1, const float* __restrict__ sl,
    const float* __restrict__ g, const float* __restrict__ bta,
    unsigned short* __restrict__ ohi, unsigned short* __restrict__ olo) {
  __shared__ float sb[4];
  float2 p = fq_params(sl, sl + 1);
  int row = blockIdx.x, t = threadIdx.x;
  size_t i4 = (size_t)row * 256 + t;
  float4 a = ((const float4*)parts)[i4];
  float4 b = ((const float4*)parts)[pstride4 + i4];
  float4 bc = ((const float4*)bias)[t];
  float4 r = ((const float4*)res)[i4];
  float4 xv;
  xv.x = r.x + fq1(a.x + b.x + bc.x, p.x, p.y);
  xv.y = r.y + fq1(a.y + b.y + bc.y, p.x, p.y);
  xv.z = r.z + fq1(a.z + b.z + bc.z, p.x, p.y);
  xv.w = r.w + fq1(a.w + b.w + bc.w, p.x, p.y);
  ((float4*)x1)[i4] = xv;
  float mu = block_sum256(xv.x + xv.y + xv.z + xv.w, sb) * (1.0f / DD);
  float dx = xv.x - mu, dy = xv.y - mu, dz = xv.z - mu, dw = xv.w - mu;
  float var = block_sum256(dx*dx + dy*dy + dz*dz + dw*dw, sb) * (1.0f / DD);
  float rs = 1.0f / sqrtf(var + EPSF);
  float4 gv = ((const float4*)g)[t];
  float4 bv = ((const float4*)bta)[t];
  float o0 = dx * rs * gv.x + bv.x;
  float o1 = dy * rs * gv.y + bv.y;
  float o2 = dz * rs * gv.z + bv.z;
  float o3 = dw * rs * gv.w + bv.w;
  ushort4 h, l;
  h.x = f2bf(o0); l.x = f2bf(o0 - bf2f(h.x));
  h.y = f2bf(o1); l.y = f2bf(o1 - bf2f(h.y));
  h.z = f2bf(o2); l.z = f2bf(o2 - bf2f(h.z));
  h.w = f2bf(o3); l.w = f2bf(o3 - bf2f(h.w));
  ((ushort4*)(ohi + (size_t)row * DD))[t] = h;
  ((ushort4*)(olo + (size_t)row * DD))[t] = l;
}

// Narrow MFMA GEMM (128x128 block, BK=64) — used for the o projection (small N).
__global__ __launch_bounds__(256, 3) void k_gemm_bf(
    const unsigned short* __restrict__ Ahi, const unsigned short* __restrict__ Alo,
    const unsigned short* __restrict__ Bq,
    const float* __restrict__ bias, const float* __restrict__ wsc, float* __restrict__ obs,
    float* __restrict__ C, int ldC, int K, int kLen, int segShift, size_t partStride) {
  __shared__ unsigned short sAh[128 * BK];
  __shared__ unsigned short sAl[128 * BK];
  __shared__ unsigned short sB [128 * BK];
  __shared__ float redH, redN;
  const int t = threadIdx.x;
  const int row0 = blockIdx.x * 128, col0 = blockIdx.y * 128;
  const int kOff = blockIdx.z * kLen;
  float* Cp = C + (size_t)blockIdx.z * partStride;
  const int wave = t >> 6, lane = t & 63;
  const int wr = (wave >> 1) * 64, wc = (wave & 1) * 64;
  const int fr = lane & 15, fq = lane >> 4;
  const int seg = col0 >> segShift;
  const float s = fmaxf(wsc[seg] / 127.0f, 1e-8f);
  if (t == 0) { redH = 0.f; redN = 0.f; }

  f32x4 acc[4][4];
  #pragma unroll
  for (int i = 0; i < 4; ++i)
    #pragma unroll
    for (int j = 0; j < 4; ++j) acc[i][j] = (f32x4){0.f, 0.f, 0.f, 0.f};

  const int srB = lane >> 3;          // row within 8-row group
  const int scs = lane & 7;           // LDS chunk slot (16B units, 8 per row)

  for (int k0 = kOff; k0 < kOff + kLen; k0 += BK) {
    __syncthreads();
    #pragma unroll
    for (int it = 0; it < 4; ++it) {
      int r = (wave * 4 + it) * 8 + srB;
      int g = scs ^ (r & 7);
      size_t ga = (size_t)(row0 + r) * K + k0 + g * 8;
      size_t gb = (size_t)(col0 + r) * K + k0 + g * 8;
      int ld = r * BK + scs * 8;
      gld16(Ahi + ga, &sAh[ld]);
      gld16(Alo + ga, &sAl[ld]);
      gld16(Bq + gb, &sB[ld]);
    }
    __syncthreads();
    #pragma unroll
    for (int hh = 0; hh < 2; ++hh) {
      bf16x8 ah[4], al[4], bb[4];
      #pragma unroll
      for (int i = 0; i < 4; ++i) {
        int Ra = wr + i * 16 + fr;
        int Rb = wc + i * 16 + fr;
        int ca = ((hh * 4 + fq) ^ (Ra & 7)) * 8;
        int cb = ((hh * 4 + fq) ^ (Rb & 7)) * 8;
        ah[i] = *(const bf16x8*)&sAh[Ra * BK + ca];
        al[i] = *(const bf16x8*)&sAl[Ra * BK + ca];
        bb[i] = *(const bf16x8*)&sB [Rb * BK + cb];
      }
      #pragma unroll
      for (int i = 0; i < 4; ++i)
        #pragma unroll
        for (int j = 0; j < 4; ++j) {
          acc[i][j] = __builtin_amdgcn_mfma_f32_16x16x32_bf16(ah[i], bb[j], acc[i][j], 0, 0, 0);
          acc[i][j] = __builtin_amdgcn_mfma_f32_16x16x32_bf16(al[i], bb[j], acc[i][j], 0, 0, 0);
        }
    }
  }

  float ohi = 0.f, ong = 0.f;
  #pragma unroll
  for (int i = 0; i < 4; ++i) {
    #pragma unroll
    for (int j = 0; j < 4; ++j) {
      int col = col0 + wc + j * 16 + fr;
      float bcol = bias ? bias[col] : 0.0f;
      #pragma unroll
      for (int rg = 0; rg < 4; ++rg) {
        int row = row0 + wr + i * 16 + fq * 4 + rg;
        float val = acc[i][j][rg] * s + bcol;
        if (obs) { ohi = fmaxf(ohi, val); ong = fmaxf(ong, -val); }
        Cp[(size_t)row * ldC + col] = val;
      }
    }
  }
  if (obs) {
    #pragma unroll
    for (int o = 32; o; o >>= 1) {
      ohi = fmaxf(ohi, __shfl_down(ohi, o, 64));
      ong = fmaxf(ong, __shfl_down(ong, o, 64));
    }
    if (lane == 0) { atomicMaxPos(&redH, ohi); atomicMaxPos(&redN, ong); }
    __syncthreads();
    if (t == 0) {
      atomicMaxPos(obs + 2 * seg, redH);
      atomicMaxPos(obs + 2 * seg + 1, redN);
    }
  }
}

// Wide MFMA GEMM: 128x256 block, wave tile 64x128 (acc 4x8) — MFMA-bound
// (128 MFMA per 32 ds_read_b128 per BK=64 iter). LDS 64KB, ~2 blocks/CU.
__global__ __launch_bounds__(256, 2) void k_gemm_wide(
    const unsigned short* __restrict__ Ahi, const unsigned short* __restrict__ Alo,
    const unsigned short* __restrict__ Bq,
    const float* __restrict__ bias, const float* __restrict__ wsc, float* __restrict__ obs,
    float* __restrict__ C, int ldC, int K, int kLen, int segShift, size_t partStride) {
  __shared__ unsigned short sAh[128 * BK];
  __shared__ unsigned short sAl[128 * BK];
  __shared__ unsigned short sB [256 * BK];
  __shared__ float redH, redN;
  const int t = threadIdx.x;
  const int row0 = blockIdx.x * 128, col0 = blockIdx.y * 256;
  const int kOff = blockIdx.z * kLen;
  float* Cp = C + (size_t)blockIdx.z * partStride;
  const int wave = t >> 6, lane = t & 63;
  const int wr = (wave >> 1) * 64, wc = (wave & 1) * 128;
  const int fr = lane & 15, fq = lane >> 4;
  const int seg = col0 >> segShift;
  const float s = fmaxf(wsc[seg] / 127.0f, 1e-8f);
  if (t == 0) { redH = 0.f; redN = 0.f; }

  f32x4 acc[4][8];
  #pragma unroll
  for (int i = 0; i < 4; ++i)
    #pragma unroll
    for (int j = 0; j < 8; ++j) acc[i][j] = (f32x4){0.f, 0.f, 0.f, 0.f};

  const int srB = lane >> 3;          // row within 8-row group
  const int scs = lane & 7;           // LDS chunk slot (16B units, 8 per row)

  for (int k0 = kOff; k0 < kOff + kLen; k0 += BK) {
    __syncthreads();
    #pragma unroll
    for (int it = 0; it < 4; ++it) {
      int r = (wave * 4 + it) * 8 + srB;
      int g = scs ^ (r & 7);
      size_t ga = (size_t)(row0 + r) * K + k0 + g * 8;
      int ld = r * BK + scs * 8;
      gld16(Ahi + ga, &sAh[ld]);
      gld16(Alo + ga, &sAl[ld]);
    }
    #pragma unroll
    for (int it = 0; it < 8; ++it) {
      int r = (wave * 8 + it) * 8 + srB;
      int g = scs ^ (r & 7);
      size_t gb = (size_t)(col0 + r) * K + k0 + g * 8;
      gld16(Bq + gb, &sB[r * BK + scs * 8]);
    }
    __syncthreads();
    #pragma unroll
    for (int hh = 0; hh < 2; ++hh) {
      bf16x8 ah[4], al[4], bb[8];
      #pragma unroll
      for (int i = 0; i < 4; ++i) {
        int Ra = wr + i * 16 + fr;
        int ca = ((hh * 4 + fq) ^ (Ra & 7)) * 8;
        ah[i] = *(const bf16x8*)&sAh[Ra * BK + ca];
        al[i] = *(const bf16x8*)&sAl[Ra * BK + ca];
      }
      #pragma unroll
      for (int j = 0; j < 8; ++j) {
        int Rb = wc + j * 16 + fr;
        int cb = ((hh * 4 + fq) ^ (Rb & 7)) * 8;
        bb[j] = *(const bf16x8*)&sB[Rb * BK + cb];
      }
      #pragma unroll
      for (int i = 0; i < 4; ++i)
        #pragma unroll
        for (int j = 0; j < 8; ++j) {
          acc[i][j] = __builtin_amdgcn_mfma_f32_16x16x32_bf16(ah[i], bb[j], acc[i][j], 0, 0, 0);
          acc[i][j] = __builtin_amdgcn_mfma_f32_16x16x32_bf16(al[i], bb[j], acc[i][j], 0, 0, 0);
        }
    }
  }

  float ohi = 0.f, ong = 0.f;
  #pragma unroll
  for (int i = 0; i < 4; ++i) {
    #pragma unroll
    for (int j = 0; j < 8; ++j) {
      int col = col0 + wc + j * 16 + fr;
      float bcol = bias ? bias[col] : 0.0f;
      #pragma unroll
      for (int rg = 0; rg < 4; ++rg) {
        int row = row0 + wr + i * 16 + fq * 4 + rg;
        float val = acc[i][j][rg] * s + bcol;
        if (obs) { ohi = fmaxf(ohi, val); ong = fmaxf(ong, -val); }
        Cp[(size_t)row * ldC + col] = val;
      }
    }
  }
  if (obs) {
    #pragma unroll
    for (int o = 32; o; o >>= 1) {
      ohi = fmaxf(ohi, __shfl_down(ohi, o, 64));
      ong = fmaxf(ong, __shfl_down(ong, o, 64));
    }
    if (lane == 0) { atomicMaxPos(&redH, ohi); atomicMaxPos(&redN, ong); }
    __syncthreads();
    if (t == 0) {
      atomicMaxPos(obs + 2 * seg, redH);
      atomicMaxPos(obs + 2 * seg + 1, redN);
    }
  }
}

// ---- MFMA attention on integer bf16 codes ----
__global__ __launch_bounds__(256) void k_attn_a_mfma(
    const unsigned short* __restrict__ qc, const unsigned short* __restrict__ kc,
    const float* __restrict__ slq, const float* __restrict__ slk,
    float* __restrict__ rowm, float* __restrict__ rowz, float* __restrict__ maxp) {
  __shared__ unsigned short ks[64 * 72];
  __shared__ float redp;
  const int t = threadIdx.x, wave = t >> 6, lane = t & 63;
  const int fr = lane & 15, fq = lane >> 4;
  const int l0 = blockIdx.x * 64, h = blockIdx.y, b = blockIdx.z;
  const float sfac = fq_params2(slq, slq + 1).x * fq_params2(slk, slk + 1).x * 0.125f;
  if (t == 0) redp = 0.f;
  const unsigned short* qrow = qc + ((size_t)(b * LL + l0 + wave * 16 + fr)) * DD + h * HDD;
  bf16x8 qa0 = *(const bf16x8*)(qrow + fq * 8);
  bf16x8 qa1 = *(const bf16x8*)(qrow + 32 + fq * 8);
  float mrun[4] = {-INFINITY, -INFINITY, -INFINITY, -INFINITY};
  float zrun[4] = {0.f, 0.f, 0.f, 0.f};
  for (int mc = 0; mc < LL; mc += 64) {
    __syncthreads();
    #pragma unroll
    for (int it = 0; it < 2; ++it) {
      int si = t + it * 256, r = si >> 3, c8 = (si & 7) * 8;
      *(bf16x8*)&ks[r * 72 + c8] =
          *(const bf16x8*)(kc + ((size_t)(b * LL + mc + r)) * DD + h * HDD + c8);
    }
    __syncthreads();
    float sv[4][4];
    #pragma unroll
    for (int j = 0; j < 4; ++j) {
      bf16x8 b0 = *(const bf16x8*)&ks[(j * 16 + fr) * 72 + fq * 8];
      bf16x8 b1 = *(const bf16x8*)&ks[(j * 16 + fr) * 72 + 32 + fq * 8];
      f32x4 sAcc = (f32x4){0.f, 0.f, 0.f, 0.f};
      sAcc = __builtin_amdgcn_mfma_f32_16x16x32_bf16(qa0, b0, sAcc, 0, 0, 0);
      sAcc = __builtin_amdgcn_mfma_f32_16x16x32_bf16(qa1, b1, sAcc, 0, 0, 0);
      #pragma unroll
      for (int rg = 0; rg < 4; ++rg) sv[j][rg] = sAcc[rg] * sfac;
    }
    #pragma unroll
    for (int rg = 0; rg < 4; ++rg) {
      float nm = mrun[rg];
      #pragma unroll
      for (int j = 0; j < 4; ++j) nm = fmaxf(nm, sv[j][rg]);
      float z = zrun[rg] * expf(mrun[rg] - nm);
      #pragma unroll
      for (int j = 0; j < 4; ++j) z += expf(sv[j][rg] - nm);
      zrun[rg] = z; mrun[rg] = nm;
    }
  }
  #pragma unroll
  for (int off = 1; off < 16; off <<= 1) {
    #pragma unroll
    for (int rg = 0; rg < 4; ++rg) {
      float om = __shfl_xor(mrun[rg], off, 64);
      float oz = __shfl_xor(zrun[rg], off, 64);
      float nm = fmaxf(mrun[rg], om);
      zrun[rg] = zrun[rg] * expf(mrun[rg] - nm) + oz * expf(om - nm);
      mrun[rg] = nm;
    }
  }
  if (fr == 0) {
    int rid = (b * HH + h) * LL + l0 + wave * 16 + fq * 4;
    float lmax = 0.f;
    #pragma unroll
    for (int rg = 0; rg < 4; ++rg) {
      rowm[rid + rg] = mrun[rg]; rowz[rid + rg] = zrun[rg];
      lmax = fmaxf(lmax, 1.0f / zrun[rg]);
    }
    atomicMaxPos(&redp, lmax);
  }
  __syncthreads();
  if (t == 0) atomicMaxPos(maxp, redp);
}

__global__ __launch_bounds__(256) void k_attn_b_mfma(
    const unsigned short* __restrict__ qc, const unsigned short* __restrict__ kc,
    const unsigned short* __restrict__ vt,
    const float* __restrict__ slq, const float* __restrict__ slk, const float* __restrict__ slv,
    const float* __restrict__ rowm, const float* __restrict__ rowz,
    const float* __restrict__ maxp,
    unsigned short* __restrict__ chi, unsigned short* __restrict__ clo) {
  __shared__ unsigned short ks[64 * 72];
  __shared__ unsigned short vs[64 * 72];
  __shared__ unsigned short ps[4][16 * 72];
  const int t = threadIdx.x, wave = t >> 6, lane = t & 63;
  const int fr = lane & 15, fq = lane >> 4;
  const int l0 = blockIdx.x * 64, h = blockIdx.y, b = blockIdx.z;
  const float sfac = fq_params2(slq, slq + 1).x * fq_params2(slk, slk + 1).x * 0.125f;
  const float sv2 = fq_params2(slv, slv + 1).x;
  const float pscale = fmaxf(maxp[0] / 255.0f, 1e-8f);
  const float ipscale = 1.0f / pscale;
  const int ridb = (b * HH + h) * LL + l0 + wave * 16 + fq * 4;
  float rm[4], rzi[4];
  #pragma unroll
  for (int rg = 0; rg < 4; ++rg) { rm[rg] = rowm[ridb + rg]; rzi[rg] = 1.0f / rowz[ridb + rg]; }
  const unsigned short* qrow = qc + ((size_t)(b * LL + l0 + wave * 16 + fr)) * DD + h * HDD;
  bf16x8 qa0 = *(const bf16x8*)(qrow + fq * 8);
  bf16x8 qa1 = *(const bf16x8*)(qrow + 32 + fq * 8);
  f32x4 acc[4];
  #pragma unroll
  for (int jd = 0; jd < 4; ++jd) acc[jd] = (f32x4){0.f, 0.f, 0.f, 0.f};

  for (int mc = 0; mc < LL; mc += 64) {
    __syncthreads();
    #pragma unroll
    for (int it = 0; it < 2; ++it) {
      int si = t + it * 256, r = si >> 3, c8 = (si & 7) * 8;
      *(bf16x8*)&ks[r * 72 + c8] =
          *(const bf16x8*)(kc + ((size_t)(b * LL + mc + r)) * DD + h * HDD + c8);
      *(bf16x8*)&vs[r * 72 + c8] =
          *(const bf16x8*)(vt + ((size_t)((b * HH + h) * HDD + r)) * LL + mc + c8);
    }
    __syncthreads();
    #pragma unroll
    for (int j = 0; j < 4; ++j) {
      bf16x8 b0 = *(const bf16x8*)&ks[(j * 16 + fr) * 72 + fq * 8];
      bf16x8 b1 = *(const bf16x8*)&ks[(j * 16 + fr) * 72 + 32 + fq * 8];
      f32x4 sAcc = (f32x4){0.f, 0.f, 0.f, 0.f};
      sAcc = __builtin_amdgcn_mfma_f32_16x16x32_bf16(qa0, b0, sAcc, 0, 0, 0);
      sAcc = __builtin_amdgcn_mfma_f32_16x16x32_bf16(qa1, b1, sAcc, 0, 0, 0);
      #pragma unroll
      for (int rg = 0; rg < 4; ++rg) {
        float p = expf(sAcc[rg] * sfac - rm[rg]) * rzi[rg];
        float q = fminf(fmaxf(rintf(p * ipscale), 0.0f), 255.0f);
        ps[wave][(fq * 4 + rg) * 72 + j * 16 + fr] = f2bf(q);
      }
    }
    __syncthreads();
    bf16x8 pa0 = *(const bf16x8*)&ps[wave][fr * 72 + fq * 8];
    bf16x8 pa1 = *(const bf16x8*)&ps[wave][fr * 72 + 32 + fq * 8];
    #pragma unroll
    for (int jd = 0; jd < 4; ++jd) {
      bf16x8 vb0 = *(const bf16x8*)&vs[(jd * 16 + fr) * 72 + fq * 8];
      bf16x8 vb1 = *(const bf16x8*)&vs[(jd * 16 + fr) * 72 + 32 + fq * 8];
      acc[jd] = __builtin_amdgcn_mfma_f32_16x16x32_bf16(pa0, vb0, acc[jd], 0, 0, 0);
      acc[jd] = __builtin_amdgcn_mfma_f32_16x16x32_bf16(pa1, vb1, acc[jd], 0, 0, 0);
    }
  }
  const float osc = pscale * sv2;
  #pragma unroll
  for (int jd = 0; jd < 4; ++jd)
    #pragma unroll
    for (int rg = 0; rg < 4; ++rg) {
      int row = l0 + wave * 16 + fq * 4 + rg;
      size_t cidx = ((size_t)(b * LL + row)) * DD + h * HDD + jd * 16 + fr;
      float val = acc[jd][rg] * osc;
      unsigned short hh = f2bf(val);
      chi[cidx] = hh;
      clo[cidx] = f2bf(val - bf2f(hh));
    }
}

extern "C" void kernel_launch(void* const* d_in, const int* in_sizes, int n_in,
                              void* d_out, int out_size, void* d_ws, size_t ws_size,
                              hipStream_t stream) {
  const float* x    = (const float*)d_in[0];
  const float* ln1g = (const float*)d_in[1];
  const float* ln1b = (const float*)d_in[2];
  const float* wq   = (const float*)d_in[3];
  const float* bq   = (const float*)d_in[4];
  const float* wk   = (const float*)d_in[5];
  const float* bk   = (const float*)d_in[6];
  const float* wv   = (const float*)d_in[7];
  const float* bv   = (const float*)d_in[8];
  const float* wo   = (const float*)d_in[9];
  const float* bo   = (const float*)d_in[10];
  const float* ln2g = (const float*)d_in[11];
  const float* ln2b = (const float*)d_in[12];
  const float* wfc  = (const float*)d_in[13];
  const float* bfc  = (const float*)d_in[14];
  const float* wpj  = (const float*)d_in[15];
  const float* bpj  = (const float*)d_in[16];
  float* out = (float*)d_out;
  float* ws = (float*)d_ws;

  size_t off = 0;
  float* scal = ws + off; off += 256;
  float* bcat = ws + off; off += 3072;
  unsigned short* wcatQ = (unsigned short*)(ws + off); off += (size_t)3072*DD/2;   // q,k,v stacked
  unsigned short* woQ   = (unsigned short*)(ws + off); off += (size_t)DD*DD/2;
  unsigned short* wfcQ  = (unsigned short*)(ws + off); off += (size_t)FFD*DD/2;
  unsigned short* wpjQ  = (unsigned short*)(ws + off); off += (size_t)DD*FFD/2;
  unsigned short* abhi  = (unsigned short*)(ws + off); off += (size_t)MTOK*DD/2;   // h1 -> ctx -> h2
  unsigned short* ablo  = (unsigned short*)(ws + off); off += (size_t)MTOK*DD/2;
  float* qkvb = ws + off; off += (size_t)MTOK*3072;   // raw qkv; later opart[2]; later gel hi
  float* x1rg = ws + off; off += (size_t)MTOK*DD;     // first qcod+kcod; later x1
  unsigned short* vtc = (unsigned short*)(ws + off); off += (size_t)MTOK*DD/2;
  float* rowm = ws + off; off += (size_t)BB*HH*LL;
  float* rowz = ws + off; off += (size_t)BB*HH*LL;
  float* fcb  = ws + off; off += (size_t)MTOK*FFD;    // fc raw; later pjpart[4]
  unsigned short* gello = (unsigned short*)(ws + off); off += (size_t)MTOK*FFD/2;

  unsigned short* qcod = (unsigned short*)x1rg;
  unsigned short* kcod = (unsigned short*)(x1rg + (size_t)MTOK*DD/2);
  float* x1 = x1rg;
  float* opart = qkvb;                       // 2 x [4096x1024]
  unsigned short* gelhi = (unsigned short*)qkvb;
  float* pjpart = fcb;                       // 4 x [4096x1024]

  const int ND  = MTOK*DD/4;
  const int NF  = MTOK*FFD/4;
  const int NW  = DD*DD/4;
  const int NWF = DD*FFD/4;
  const size_t PS4 = (size_t)MTOK*DD/4;      // part stride in float4s

  auto g4 = [](int n4){ int g = (n4 + 255) / 256; return g > 4096 ? 4096 : g; };

  k_init_bcat<<<12, 256, 0, stream>>>(scal, bq, bk, bv, bcat);

  WSet wset;
  wset.w[0] = wq;  wset.q[0] = wcatQ;                   wset.n4[0] = NW;
  wset.w[1] = wk;  wset.q[1] = wcatQ + (size_t)DD*DD;   wset.n4[1] = NW;
  wset.w[2] = wv;  wset.q[2] = wcatQ + (size_t)2*DD*DD; wset.n4[2] = NW;
  wset.w[3] = wo;  wset.q[3] = woQ;                     wset.n4[3] = NW;
  wset.w[4] = wfc; wset.q[4] = wfcQ;                    wset.n4[4] = NWF;
  wset.w[5] = wpj; wset.q[5] = wpjQ;                    wset.n4[5] = NWF;

  k_absmax6<<<dim3(512, 6), 256, 0, stream>>>(wset, scal);
  k_quantw6<<<dim3(512, 6), 256, 0, stream>>>(wset, scal);

  k_ln_bf<<<MTOK, 256, 0, stream>>>(x, ln1g, ln1b, abhi, ablo);

  // fused q,k,v GEMM (wide): rows on x, 12 col-tiles of 256; obs pairs at scal+6
  k_gemm_wide<<<dim3(32, 12, 1), 256, 0, stream>>>(abhi, ablo, wcatQ, bcat, scal+0, scal+6,
                                                   qkvb, 3072, DD, DD, 10, 0);

  k_quant_codes<<<g4(ND), 256, 0, stream>>>(qkvb, 0,    qcod, scal+6);
  k_quant_codes<<<g4(ND), 256, 0, stream>>>(qkvb, 1024, kcod, scal+8);
  k_quant_codes_vt<<<dim3(8, 16, 8), 256, 0, stream>>>(qkvb, vtc, scal+10);

  k_attn_a_mfma<<<dim3(8, 16, 8), 256, 0, stream>>>(qcod, kcod, scal+6, scal+8,
                                                    rowm, rowz, scal+18);
  k_attn_b_mfma<<<dim3(8, 16, 8), 256, 0, stream>>>(qcod, kcod, vtc, scal+6, scal+8, scal+10,
                                                    rowm, rowz, scal+18, abhi, ablo);

  // o GEMM split-K x2 (narrow)
  k_gemm_bf<<<dim3(32, 8, 2), 256, 0, stream>>>(abhi, ablo, woQ, nullptr, scal+3, nullptr,
                                                opart, DD, DD, 512, 20, (size_t)MTOK*DD);
  k_sum_minmax<<<2048, 256, 0, stream>>>(opart, PS4, 2, bo, ND, 255, scal+19);
  // fused residual + LN2 -> x1 + h2 hi/lo
  k_res_ln<<<MTOK, 256, 0, stream>>>(opart, PS4, bo, x, x1, scal+19,
                                     ln2g, ln2b, abhi, ablo);

  // fc GEMM (wide): N=4096, fused bias+obs
  k_gemm_wide<<<dim3(32, 16, 1), 256, 0, stream>>>(abhi, ablo, wfcQ, bfc, scal+4, scal+21,
                                                   fcb, FFD, DD, DD, 20, 0);
  k_gelu_codes<<<g4(NF), 256, 0, stream>>>(fcb, gelhi, gello, NF, scal+21);

  // pj GEMM (wide) split-K x4 over K=4096
  k_gemm_wide<<<dim3(32, 4, 4), 256, 0, stream>>>(gelhi, gello, wpjQ, nullptr, scal+5, nullptr,
                                                  pjpart, DD, FFD, 1024, 20, (size_t)MTOK*DD);
  k_sum_minmax<<<2048, 256, 0, stream>>>(pjpart, PS4, 4, bpj, ND, 255, scal+23);
  k_quant_res2<<<g4(ND), 256, 0, stream>>>(pjpart, PS4, 4, bpj, x1, out, ND, 255, scal+23);
}

// Round 8
// 573.678 us; speedup vs baseline: 1.0837x; 1.0837x over previous
//
#include <hip/hip_runtime.h>
#include <cmath>

#define BB 8
#define LL 512
#define DD 1024
#define HH 16
#define HDD 64
#define FFD 4096
#define MTOK (BB*LL)
#define EPSF 1e-5f
#define BK 64

typedef __attribute__((ext_vector_type(8))) _Float16 f16x8;
typedef __attribute__((ext_vector_type(4))) float f32x4;

// scal slots: 0..5 weight absmax (q,k,v,o,fc,pj)
// 6,7 q obs | 8,9 k | 10,11 v | 18 maxp | 19,20 o | 21,22 fc | 23,24 pj

struct WSet {
  const float* w[6];
  unsigned short* q[6];
  int n4[6];
};

__device__ inline void atomicMaxPos(float* addr, float v) {
  atomicMax((unsigned int*)addr, __float_as_uint(v));  // v >= 0, slot init 0
}

__device__ inline unsigned short f2h(float x) {  // fp32 -> fp16 RNE (exact for ints <= 2048)
  _Float16 h = (_Float16)x;
  union { _Float16 hf; unsigned short u; } cv; cv.hf = h;
  return cv.u;
}

// async 16B global->LDS; dest addresses are base+lane*16 by construction
__device__ __forceinline__ void gld16(const unsigned short* g, unsigned short* l) {
  __builtin_amdgcn_global_load_lds(
      (const __attribute__((address_space(1))) unsigned int*)g,
      (__attribute__((address_space(3))) unsigned int*)l, 16, 0, 0);
}

__global__ void k_init_bcat(float* __restrict__ s, const float* __restrict__ b0,
                            const float* __restrict__ b1, const float* __restrict__ b2,
                            float* __restrict__ dst) {
  int i = blockIdx.x * blockDim.x + threadIdx.x;
  if (i < 256) s[i] = 0.0f;
  if (i < 3072) dst[i] = i < 1024 ? b0[i] : (i < 2048 ? b1[i - 1024] : b2[i - 2048]);
}

__global__ void k_absmax6(WSet ws, float* __restrict__ scal) {
  const int id = blockIdx.y;
  const float4* w4 = (const float4*)ws.w[id];
  const int n4 = ws.n4[id];
  float m = 0.0f;
  for (int i = blockIdx.x * blockDim.x + threadIdx.x; i < n4; i += gridDim.x * blockDim.x) {
    float4 v = w4[i];
    m = fmaxf(m, fmaxf(fmaxf(fabsf(v.x), fabsf(v.y)), fmaxf(fabsf(v.z), fabsf(v.w))));
  }
  #pragma unroll
  for (int o = 32; o; o >>= 1) m = fmaxf(m, __shfl_down(m, o, 64));
  __shared__ float sb[4];
  int lane = threadIdx.x & 63, wid = threadIdx.x >> 6;
  if (lane == 0) sb[wid] = m;
  __syncthreads();
  if (threadIdx.x == 0) atomicMaxPos(scal + id, fmaxf(fmaxf(sb[0], sb[1]), fmaxf(sb[2], sb[3])));
}

// weights -> fp16 INTEGER codes (qint in [-128,127], exact in fp16)
__global__ void k_quantw6(WSet ws, const float* __restrict__ scal) {
  const int id = blockIdx.y;
  float s = fmaxf(scal[id] / 127.0f, 1e-8f);
  const float4* w4 = (const float4*)ws.w[id];
  ushort4* q4 = (ushort4*)ws.q[id];
  const int n4 = ws.n4[id];
  for (int i = blockIdx.x * blockDim.x + threadIdx.x; i < n4; i += gridDim.x * blockDim.x) {
    float4 v = w4[i];
    ushort4 o;
    o.x = f2h(fminf(fmaxf(rintf(v.x / s), -128.0f), 127.0f));
    o.y = f2h(fminf(fmaxf(rintf(v.y / s), -128.0f), 127.0f));
    o.z = f2h(fminf(fmaxf(rintf(v.z / s), -128.0f), 127.0f));
    o.w = f2h(fminf(fmaxf(rintf(v.w / s), -128.0f), 127.0f));
    q4[i] = o;
  }
}

__device__ inline float2 fq_params(const float* sHi, const float* sNeg) {
  float hi = *sHi, lo = -(*sNeg);
  float scale = fmaxf((hi - lo) / 255.0f, 1e-8f);
  float zp = rintf(-lo / scale);
  return make_float2(scale, zp);
}
__device__ inline float fq1(float x, float scale, float zp) {
  float q = fminf(fmaxf(rintf(x / scale) + zp, 0.0f), 255.0f);
  return (q - zp) * scale;
}
__device__ inline float2 fq_params2(const float* sHi, const float* sNeg) {
  float2 p1 = fq_params(sHi, sNeg);
  float hi2 = fq1(*sHi, p1.x, p1.y);
  float lo2 = fq1(-(*sNeg), p1.x, p1.y);
  float scale = fmaxf((hi2 - lo2) / 255.0f, 1e-8f);
  float zp = rintf(-lo2 / scale);
  return make_float2(scale, zp);
}
__device__ inline float code2(float x, float2 p1, float2 p2) {
  float v1 = fq1(x, p1.x, p1.y);
  float q = fminf(fmaxf(rintf(v1 / p2.x) + p2.y, 0.0f), 255.0f);
  return q - p2.y;  // integer in [-255,255], exact in fp16
}

// raw qkv (ld 3072) -> double-fq -> fp16 integer codes packed [4096][1024]
__global__ void k_quant_codes(const float* __restrict__ src, int colBase,
                              unsigned short* __restrict__ oc, const float* __restrict__ sl) {
  float2 p1 = fq_params(sl, sl + 1);
  float2 p2 = fq_params2(sl, sl + 1);
  const int n4 = MTOK * DD / 4;
  for (int i = blockIdx.x * blockDim.x + threadIdx.x; i < n4; i += gridDim.x * blockDim.x) {
    int row = i >> 8, c = (i & 255) * 4;
    float4 v = *(const float4*)(src + (size_t)row * 3072 + colBase + c);
    ushort4 o;
    o.x = f2h(code2(v.x, p1, p2)); o.y = f2h(code2(v.y, p1, p2));
    o.z = f2h(code2(v.z, p1, p2)); o.w = f2h(code2(v.w, p1, p2));
    *(ushort4*)&oc[(size_t)row * DD + c] = o;
  }
}

// V codes per-head transposed: vt[((b*H+h)*64+d)*512 + m]; src ld 3072, col base 2048
__global__ __launch_bounds__(256) void k_quant_codes_vt(
    const float* __restrict__ src, unsigned short* __restrict__ vt,
    const float* __restrict__ sl) {
  __shared__ unsigned short tile[64 * 68];
  float2 p1 = fq_params(sl, sl + 1);
  float2 p2 = fq_params2(sl, sl + 1);
  const int m0 = blockIdx.x * 64, h = blockIdx.y, b = blockIdx.z;
  const int t = threadIdx.x;
  const int r = t >> 2, c0 = (t & 3) * 16;
  const float* s4 = src + ((size_t)(b * LL + m0 + r)) * 3072 + 2048 + h * HDD + c0;
  #pragma unroll
  for (int i = 0; i < 4; ++i) {
    float4 v = *(const float4*)(s4 + i * 4);
    ushort4 o;
    o.x = f2h(code2(v.x, p1, p2)); o.y = f2h(code2(v.y, p1, p2));
    o.z = f2h(code2(v.z, p1, p2)); o.w = f2h(code2(v.w, p1, p2));
    *(ushort4*)&tile[r * 68 + c0 + i * 4] = o;
  }
  __syncthreads();
  const int dr = t >> 2, ms = (t & 3) * 16;
  unsigned short* dst = vt + ((size_t)((b * HH + h) * HDD + dr)) * LL + m0 + ms;
  #pragma unroll
  for (int i = 0; i < 4; ++i) {
    ushort4 o;
    o.x = tile[(ms + i * 4 + 0) * 68 + dr];
    o.y = tile[(ms + i * 4 + 1) * 68 + dr];
    o.z = tile[(ms + i * 4 + 2) * 68 + dr];
    o.w = tile[(ms + i * 4 + 3) * 68 + dr];
    *(ushort4*)(dst + i * 4) = o;
  }
}

// lin = sum(parts) + bias -> minmax observer
__global__ void k_sum_minmax(const float* __restrict__ parts, size_t pstride4, int np,
                             const float* __restrict__ bias, int n4, int cmask,
                             float* __restrict__ sl) {
  float hi = 0.0f, ng = 0.0f;
  for (int i = blockIdx.x * blockDim.x + threadIdx.x; i < n4; i += gridDim.x * blockDim.x) {
    float4 bc = *(const float4*)(bias + (i & cmask) * 4);
    float vx = bc.x, vy = bc.y, vz = bc.z, vw = bc.w;
    for (int j = 0; j < np; ++j) {
      float4 a = ((const float4*)parts)[j * pstride4 + i];
      vx += a.x; vy += a.y; vz += a.z; vw += a.w;
    }
    hi = fmaxf(hi, fmaxf(fmaxf(vx, vy), fmaxf(vz, vw)));
    ng = fmaxf(ng, fmaxf(fmaxf(-vx, -vy), fmaxf(-vz, -vw)));
  }
  #pragma unroll
  for (int o = 32; o; o >>= 1) {
    hi = fmaxf(hi, __shfl_down(hi, o, 64));
    ng = fmaxf(ng, __shfl_down(ng, o, 64));
  }
  __shared__ float sh[4], sn[4];
  int lane = threadIdx.x & 63, wid = threadIdx.x >> 6;
  if (lane == 0) { sh[wid] = hi; sn[wid] = ng; }
  __syncthreads();
  if (threadIdx.x == 0) {
    atomicMaxPos(sl, fmaxf(fmaxf(sh[0], sh[1]), fmaxf(sh[2], sh[3])));
    atomicMaxPos(sl + 1, fmaxf(fmaxf(sn[0], sn[1]), fmaxf(sn[2], sn[3])));
  }
}

// out = res + fq(sum(parts)+bias)
__global__ void k_quant_res2(const float* __restrict__ parts, size_t pstride4, int np,
                             const float* __restrict__ bias, const float* __restrict__ res,
                             float* __restrict__ out, int n4, int cmask,
                             const float* __restrict__ sl) {
  float2 p = fq_params(sl, sl + 1);
  for (int i = blockIdx.x * blockDim.x + threadIdx.x; i < n4; i += gridDim.x * blockDim.x) {
    float4 bc = *(const float4*)(bias + (i & cmask) * 4);
    float vx = bc.x, vy = bc.y, vz = bc.z, vw = bc.w;
    for (int j = 0; j < np; ++j) {
      float4 a = ((const float4*)parts)[j * pstride4 + i];
      vx += a.x; vy += a.y; vz += a.z; vw += a.w;
    }
    float4 r = ((const float4*)res)[i];
    float4 o;
    o.x = r.x + fq1(vx, p.x, p.y);
    o.y = r.y + fq1(vy, p.x, p.y);
    o.z = r.z + fq1(vz, p.x, p.y);
    o.w = r.w + fq1(vw, p.x, p.y);
    ((float4*)out)[i] = o;
  }
}

__device__ inline float gelu_exact(float g) {
  return 0.5f * g * (1.0f + erff(g * 0.7071067811865475f));
}

// fc raw -> gelu(fq(.)) -> fp16
__global__ void k_gelu_h(const float* __restrict__ x, unsigned short* __restrict__ gh,
                         int n4, const float* __restrict__ sl) {
  float2 p = fq_params(sl, sl + 1);
  for (int i = blockIdx.x * blockDim.x + threadIdx.x; i < n4; i += gridDim.x * blockDim.x) {
    float4 v = ((const float4*)x)[i];
    ushort4 h;
    h.x = f2h(gelu_exact(fq1(v.x, p.x, p.y)));
    h.y = f2h(gelu_exact(fq1(v.y, p.x, p.y)));
    h.z = f2h(gelu_exact(fq1(v.z, p.x, p.y)));
    h.w = f2h(gelu_exact(fq1(v.w, p.x, p.y)));
    ((ushort4*)gh)[i] = h;
  }
}

__device__ inline float block_sum256(float v, float* sb) {
  #pragma unroll
  for (int o = 32; o; o >>= 1) v += __shfl_down(v, o, 64);
  int lane = threadIdx.x & 63, wid = threadIdx.x >> 6;
  __syncthreads();
  if (lane == 0) sb[wid] = v;
  __syncthreads();
  return sb[0] + sb[1] + sb[2] + sb[3];
}

// LayerNorm -> fp16
__global__ __launch_bounds__(256) void k_ln_h(const float* __restrict__ x, const float* __restrict__ g,
                                              const float* __restrict__ bta,
                                              unsigned short* __restrict__ oh) {
  __shared__ float sb[4];
  int row = blockIdx.x;
  const float4* xr = (const float4*)(x + (size_t)row * DD);
  float4 v = xr[threadIdx.x];
  float mu = block_sum256(v.x + v.y + v.z + v.w, sb) * (1.0f / DD);
  float dx = v.x - mu, dy = v.y - mu, dz = v.z - mu, dw = v.w - mu;
  float var = block_sum256(dx*dx + dy*dy + dz*dz + dw*dw, sb) * (1.0f / DD);
  float rs = 1.0f / sqrtf(var + EPSF);
  float4 gv = ((const float4*)g)[threadIdx.x];
  float4 bv = ((const float4*)bta)[threadIdx.x];
  ushort4 h;
  h.x = f2h(dx * rs * gv.x + bv.x);
  h.y = f2h(dy * rs * gv.y + bv.y);
  h.z = f2h(dz * rs * gv.z + bv.z);
  h.w = f2h(dw * rs * gv.w + bv.w);
  ((ushort4*)(oh + (size_t)row * DD))[threadIdx.x] = h;
}

// fused: x1 = res + fq(p0+p1+bias), then LayerNorm(x1) -> fp16 (one block per row)
__global__ __launch_bounds__(256) void k_res_ln(
    const float* __restrict__ parts, size_t pstride4,
    const float* __restrict__ bias, const float* __restrict__ res,
    float* __restrict__ x1, const float* __restrict__ sl,
    const float* __restrict__ g, const float* __restrict__ bta,
    unsigned short* __restrict__ oh) {
  __shared__ float sb[4];
  float2 p = fq_params(sl, sl + 1);
  int row = blockIdx.x, t = threadIdx.x;
  size_t i4 = (size_t)row * 256 + t;
  float4 a = ((const float4*)parts)[i4];
  float4 b = ((const float4*)parts)[pstride4 + i4];
  float4 bc = ((const float4*)bias)[t];
  float4 r = ((const float4*)res)[i4];
  float4 xv;
  xv.x = r.x + fq1(a.x + b.x + bc.x, p.x, p.y);
  xv.y = r.y + fq1(a.y + b.y + bc.y, p.x, p.y);
  xv.z = r.z + fq1(a.z + b.z + bc.z, p.x, p.y);
  xv.w = r.w + fq1(a.w + b.w + bc.w, p.x, p.y);
  ((float4*)x1)[i4] = xv;
  float mu = block_sum256(xv.x + xv.y + xv.z + xv.w, sb) * (1.0f / DD);
  float dx = xv.x - mu, dy = xv.y - mu, dz = xv.z - mu, dw = xv.w - mu;
  float var = block_sum256(dx*dx + dy*dy + dz*dz + dw*dw, sb) * (1.0f / DD);
  float rs = 1.0f / sqrtf(var + EPSF);
  float4 gv = ((const float4*)g)[t];
  float4 bv = ((const float4*)bta)[t];
  ushort4 h;
  h.x = f2h(dx * rs * gv.x + bv.x);
  h.y = f2h(dy * rs * gv.y + bv.y);
  h.z = f2h(dz * rs * gv.z + bv.z);
  h.w = f2h(dw * rs * gv.w + bv.w);
  ((ushort4*)(oh + (size_t)row * DD))[t] = h;
}

// Narrow MFMA GEMM (128x128 block, BK=64), fp16 A x fp16 weight codes, single MFMA.
__global__ __launch_bounds__(256, 4) void k_gemm_h(
    const unsigned short* __restrict__ Aq, const unsigned short* __restrict__ Bq,
    const float* __restrict__ bias, const float* __restrict__ wsc, float* __restrict__ obs,
    float* __restrict__ C, int ldC, int K, int kLen, int segShift, size_t partStride) {
  __shared__ unsigned short sA[128 * BK];
  __shared__ unsigned short sB[128 * BK];
  __shared__ float redH, redN;
  const int t = threadIdx.x;
  const int row0 = blockIdx.x * 128, col0 = blockIdx.y * 128;
  const int kOff = blockIdx.z * kLen;
  float* Cp = C + (size_t)blockIdx.z * partStride;
  const int wave = t >> 6, lane = t & 63;
  const int wr = (wave >> 1) * 64, wc = (wave & 1) * 64;
  const int fr = lane & 15, fq = lane >> 4;
  const int seg = col0 >> segShift;
  const float s = fmaxf(wsc[seg] / 127.0f, 1e-8f);
  if (t == 0) { redH = 0.f; redN = 0.f; }

  f32x4 acc[4][4];
  #pragma unroll
  for (int i = 0; i < 4; ++i)
    #pragma unroll
    for (int j = 0; j < 4; ++j) acc[i][j] = (f32x4){0.f, 0.f, 0.f, 0.f};

  const int srB = lane >> 3;          // row within 8-row group
  const int scs = lane & 7;           // LDS chunk slot (16B units, 8 per row)

  for (int k0 = kOff; k0 < kOff + kLen; k0 += BK) {
    __syncthreads();
    #pragma unroll
    for (int it = 0; it < 4; ++it) {
      int r = (wave * 4 + it) * 8 + srB;
      int g = scs ^ (r & 7);
      size_t ga = (size_t)(row0 + r) * K + k0 + g * 8;
      size_t gb = (size_t)(col0 + r) * K + k0 + g * 8;
      int ld = r * BK + scs * 8;
      gld16(Aq + ga, &sA[ld]);
      gld16(Bq + gb, &sB[ld]);
    }
    __syncthreads();
    #pragma unroll
    for (int hh = 0; hh < 2; ++hh) {
      f16x8 av[4], bb[4];
      #pragma unroll
      for (int i = 0; i < 4; ++i) {
        int Ra = wr + i * 16 + fr;
        int Rb = wc + i * 16 + fr;
        av[i] = *(const f16x8*)&sA[Ra * BK + (((hh * 4 + fq) ^ (Ra & 7)) * 8)];
        bb[i] = *(const f16x8*)&sB[Rb * BK + (((hh * 4 + fq) ^ (Rb & 7)) * 8)];
      }
      #pragma unroll
      for (int i = 0; i < 4; ++i)
        #pragma unroll
        for (int j = 0; j < 4; ++j)
          acc[i][j] = __builtin_amdgcn_mfma_f32_16x16x32_f16(av[i], bb[j], acc[i][j], 0, 0, 0);
    }
  }

  float ohi = 0.f, ong = 0.f;
  #pragma unroll
  for (int i = 0; i < 4; ++i) {
    #pragma unroll
    for (int j = 0; j < 4; ++j) {
      int col = col0 + wc + j * 16 + fr;
      float bcol = bias ? bias[col] : 0.0f;
      #pragma unroll
      for (int rg = 0; rg < 4; ++rg) {
        int row = row0 + wr + i * 16 + fq * 4 + rg;
        float val = acc[i][j][rg] * s + bcol;
        if (obs) { ohi = fmaxf(ohi, val); ong = fmaxf(ong, -val); }
        Cp[(size_t)row * ldC + col] = val;
      }
    }
  }
  if (obs) {
    #pragma unroll
    for (int o = 32; o; o >>= 1) {
      ohi = fmaxf(ohi, __shfl_down(ohi, o, 64));
      ong = fmaxf(ong, __shfl_down(ong, o, 64));
    }
    if (lane == 0) { atomicMaxPos(&redH, ohi); atomicMaxPos(&redN, ong); }
    __syncthreads();
    if (t == 0) {
      atomicMaxPos(obs + 2 * seg, redH);
      atomicMaxPos(obs + 2 * seg + 1, redN);
    }
  }
}

// Wide MFMA GEMM: 128x256 block, wave tile 64x128 (acc 4x8), fp16, single MFMA.
__global__ __launch_bounds__(256, 2) void k_gemm_wide(
    const unsigned short* __restrict__ Aq, const unsigned short* __restrict__ Bq,
    const float* __restrict__ bias, const float* __restrict__ wsc, float* __restrict__ obs,
    float* __restrict__ C, int ldC, int K, int kLen, int segShift, size_t partStride) {
  __shared__ unsigned short sA[128 * BK];
  __shared__ unsigned short sB[256 * BK];
  __shared__ float redH, redN;
  const int t = threadIdx.x;
  const int row0 = blockIdx.x * 128, col0 = blockIdx.y * 256;
  const int kOff = blockIdx.z * kLen;
  float* Cp = C + (size_t)blockIdx.z * partStride;
  const int wave = t >> 6, lane = t & 63;
  const int wr = (wave >> 1) * 64, wc = (wave & 1) * 128;
  const int fr = lane & 15, fq = lane >> 4;
  const int seg = col0 >> segShift;
  const float s = fmaxf(wsc[seg] / 127.0f, 1e-8f);
  if (t == 0) { redH = 0.f; redN = 0.f; }

  f32x4 acc[4][8];
  #pragma unroll
  for (int i = 0; i < 4; ++i)
    #pragma unroll
    for (int j = 0; j < 8; ++j) acc[i][j] = (f32x4){0.f, 0.f, 0.f, 0.f};

  const int srB = lane >> 3;
  const int scs = lane & 7;

  for (int k0 = kOff; k0 < kOff + kLen; k0 += BK) {
    __syncthreads();
    #pragma unroll
    for (int it = 0; it < 4; ++it) {
      int r = (wave * 4 + it) * 8 + srB;
      int g = scs ^ (r & 7);
      size_t ga = (size_t)(row0 + r) * K + k0 + g * 8;
      gld16(Aq + ga, &sA[r * BK + scs * 8]);
    }
    #pragma unroll
    for (int it = 0; it < 8; ++it) {
      int r = (wave * 8 + it) * 8 + srB;
      int g = scs ^ (r & 7);
      size_t gb = (size_t)(col0 + r) * K + k0 + g * 8;
      gld16(Bq + gb, &sB[r * BK + scs * 8]);
    }
    __syncthreads();
    #pragma unroll
    for (int hh = 0; hh < 2; ++hh) {
      f16x8 av[4], bb[8];
      #pragma unroll
      for (int i = 0; i < 4; ++i) {
        int Ra = wr + i * 16 + fr;
        av[i] = *(const f16x8*)&sA[Ra * BK + (((hh * 4 + fq) ^ (Ra & 7)) * 8)];
      }
      #pragma unroll
      for (int j = 0; j < 8; ++j) {
        int Rb = wc + j * 16 + fr;
        bb[j] = *(const f16x8*)&sB[Rb * BK + (((hh * 4 + fq) ^ (Rb & 7)) * 8)];
      }
      #pragma unroll
      for (int i = 0; i < 4; ++i)
        #pragma unroll
        for (int j = 0; j < 8; ++j)
          acc[i][j] = __builtin_amdgcn_mfma_f32_16x16x32_f16(av[i], bb[j], acc[i][j], 0, 0, 0);
    }
  }

  float ohi = 0.f, ong = 0.f;
  #pragma unroll
  for (int i = 0; i < 4; ++i) {
    #pragma unroll
    for (int j = 0; j < 8; ++j) {
      int col = col0 + wc + j * 16 + fr;
      float bcol = bias ? bias[col] : 0.0f;
      #pragma unroll
      for (int rg = 0; rg < 4; ++rg) {
        int row = row0 + wr + i * 16 + fq * 4 + rg;
        float val = acc[i][j][rg] * s + bcol;
        if (obs) { ohi = fmaxf(ohi, val); ong = fmaxf(ong, -val); }
        Cp[(size_t)row * ldC + col] = val;
      }
    }
  }
  if (obs) {
    #pragma unroll
    for (int o = 32; o; o >>= 1) {
      ohi = fmaxf(ohi, __shfl_down(ohi, o, 64));
      ong = fmaxf(ong, __shfl_down(ong, o, 64));
    }
    if (lane == 0) { atomicMaxPos(&redH, ohi); atomicMaxPos(&redN, ong); }
    __syncthreads();
    if (t == 0) {
      atomicMaxPos(obs + 2 * seg, redH);
      atomicMaxPos(obs + 2 * seg + 1, redN);
    }
  }
}

// ---- MFMA attention on integer fp16 codes (exact) ----
__global__ __launch_bounds__(256) void k_attn_a_mfma(
    const unsigned short* __restrict__ qc, const unsigned short* __restrict__ kc,
    const float* __restrict__ slq, const float* __restrict__ slk,
    float* __restrict__ rowm, float* __restrict__ rowz, float* __restrict__ maxp) {
  __shared__ unsigned short ks[64 * 72];
  __shared__ float redp;
  const int t = threadIdx.x, wave = t >> 6, lane = t & 63;
  const int fr = lane & 15, fq = lane >> 4;
  const int l0 = blockIdx.x * 64, h = blockIdx.y, b = blockIdx.z;
  const float sfac = fq_params2(slq, slq + 1).x * fq_params2(slk, slk + 1).x * 0.125f;
  if (t == 0) redp = 0.f;
  const unsigned short* qrow = qc + ((size_t)(b * LL + l0 + wave * 16 + fr)) * DD + h * HDD;
  f16x8 qa0 = *(const f16x8*)(qrow + fq * 8);
  f16x8 qa1 = *(const f16x8*)(qrow + 32 + fq * 8);
  float mrun[4] = {-INFINITY, -INFINITY, -INFINITY, -INFINITY};
  float zrun[4] = {0.f, 0.f, 0.f, 0.f};
  for (int mc = 0; mc < LL; mc += 64) {
    __syncthreads();
    #pragma unroll
    for (int it = 0; it < 2; ++it) {
      int si = t + it * 256, r = si >> 3, c8 = (si & 7) * 8;
      *(f16x8*)&ks[r * 72 + c8] =
          *(const f16x8*)(kc + ((size_t)(b * LL + mc + r)) * DD + h * HDD + c8);
    }
    __syncthreads();
    float sv[4][4];
    #pragma unroll
    for (int j = 0; j < 4; ++j) {
      f16x8 b0 = *(const f16x8*)&ks[(j * 16 + fr) * 72 + fq * 8];
      f16x8 b1 = *(const f16x8*)&ks[(j * 16 + fr) * 72 + 32 + fq * 8];
      f32x4 sAcc = (f32x4){0.f, 0.f, 0.f, 0.f};
      sAcc = __builtin_amdgcn_mfma_f32_16x16x32_f16(qa0, b0, sAcc, 0, 0, 0);
      sAcc = __builtin_amdgcn_mfma_f32_16x16x32_f16(qa1, b1, sAcc, 0, 0, 0);
      #pragma unroll
      for (int rg = 0; rg < 4; ++rg) sv[j][rg] = sAcc[rg] * sfac;
    }
    #pragma unroll
    for (int rg = 0; rg < 4; ++rg) {
      float nm = mrun[rg];
      #pragma unroll
      for (int j = 0; j < 4; ++j) nm = fmaxf(nm, sv[j][rg]);
      float z = zrun[rg] * expf(mrun[rg] - nm);
      #pragma unroll
      for (int j = 0; j < 4; ++j) z += expf(sv[j][rg] - nm);
      zrun[rg] = z; mrun[rg] = nm;
    }
  }
  #pragma unroll
  for (int off = 1; off < 16; off <<= 1) {
    #pragma unroll
    for (int rg = 0; rg < 4; ++rg) {
      float om = __shfl_xor(mrun[rg], off, 64);
      float oz = __shfl_xor(zrun[rg], off, 64);
      float nm = fmaxf(mrun[rg], om);
      zrun[rg] = zrun[rg] * expf(mrun[rg] - nm) + oz * expf(om - nm);
      mrun[rg] = nm;
    }
  }
  if (fr == 0) {
    int rid = (b * HH + h) * LL + l0 + wave * 16 + fq * 4;
    float lmax = 0.f;
    #pragma unroll
    for (int rg = 0; rg < 4; ++rg) {
      rowm[rid + rg] = mrun[rg]; rowz[rid + rg] = zrun[rg];
      lmax = fmaxf(lmax, 1.0f / zrun[rg]);
    }
    atomicMaxPos(&redp, lmax);
  }
  __syncthreads();
  if (t == 0) atomicMaxPos(maxp, redp);
}

__global__ __launch_bounds__(256) void k_attn_b_mfma(
    const unsigned short* __restrict__ qc, const unsigned short* __restrict__ kc,
    const unsigned short* __restrict__ vt,
    const float* __restrict__ slq, const float* __restrict__ slk, const float* __restrict__ slv,
    const float* __restrict__ rowm, const float* __restrict__ rowz,
    const float* __restrict__ maxp, unsigned short* __restrict__ ch) {
  __shared__ unsigned short ks[64 * 72];
  __shared__ unsigned short vs[64 * 72];
  __shared__ unsigned short ps[4][16 * 72];
  const int t = threadIdx.x, wave = t >> 6, lane = t & 63;
  const int fr = lane & 15, fq = lane >> 4;
  const int l0 = blockIdx.x * 64, h = blockIdx.y, b = blockIdx.z;
  const float sfac = fq_params2(slq, slq + 1).x * fq_params2(slk, slk + 1).x * 0.125f;
  const float sv2 = fq_params2(slv, slv + 1).x;
  const float pscale = fmaxf(maxp[0] / 255.0f, 1e-8f);
  const float ipscale = 1.0f / pscale;
  const int ridb = (b * HH + h) * LL + l0 + wave * 16 + fq * 4;
  float rm[4], rzi[4];
  #pragma unroll
  for (int rg = 0; rg < 4; ++rg) { rm[rg] = rowm[ridb + rg]; rzi[rg] = 1.0f / rowz[ridb + rg]; }
  const unsigned short* qrow = qc + ((size_t)(b * LL + l0 + wave * 16 + fr)) * DD + h * HDD;
  f16x8 qa0 = *(const f16x8*)(qrow + fq * 8);
  f16x8 qa1 = *(const f16x8*)(qrow + 32 + fq * 8);
  f32x4 acc[4];
  #pragma unroll
  for (int jd = 0; jd < 4; ++jd) acc[jd] = (f32x4){0.f, 0.f, 0.f, 0.f};

  for (int mc = 0; mc < LL; mc += 64) {
    __syncthreads();
    #pragma unroll
    for (int it = 0; it < 2; ++it) {
      int si = t + it * 256, r = si >> 3, c8 = (si & 7) * 8;
      *(f16x8*)&ks[r * 72 + c8] =
          *(const f16x8*)(kc + ((size_t)(b * LL + mc + r)) * DD + h * HDD + c8);
      *(f16x8*)&vs[r * 72 + c8] =
          *(const f16x8*)(vt + ((size_t)((b * HH + h) * HDD + r)) * LL + mc + c8);
    }
    __syncthreads();
    #pragma unroll
    for (int j = 0; j < 4; ++j) {
      f16x8 b0 = *(const f16x8*)&ks[(j * 16 + fr) * 72 + fq * 8];
      f16x8 b1 = *(const f16x8*)&ks[(j * 16 + fr) * 72 + 32 + fq * 8];
      f32x4 sAcc = (f32x4){0.f, 0.f, 0.f, 0.f};
      sAcc = __builtin_amdgcn_mfma_f32_16x16x32_f16(qa0, b0, sAcc, 0, 0, 0);
      sAcc = __builtin_amdgcn_mfma_f32_16x16x32_f16(qa1, b1, sAcc, 0, 0, 0);
      #pragma unroll
      for (int rg = 0; rg < 4; ++rg) {
        float p = expf(sAcc[rg] * sfac - rm[rg]) * rzi[rg];
        float q = fminf(fmaxf(rintf(p * ipscale), 0.0f), 255.0f);
        ps[wave][(fq * 4 + rg) * 72 + j * 16 + fr] = f2h(q);
      }
    }
    __syncthreads();
    f16x8 pa0 = *(const f16x8*)&ps[wave][fr * 72 + fq * 8];
    f16x8 pa1 = *(const f16x8*)&ps[wave][fr * 72 + 32 + fq * 8];
    #pragma unroll
    for (int jd = 0; jd < 4; ++jd) {
      f16x8 vb0 = *(const f16x8*)&vs[(jd * 16 + fr) * 72 + fq * 8];
      f16x8 vb1 = *(const f16x8*)&vs[(jd * 16 + fr) * 72 + 32 + fq * 8];
      acc[jd] = __builtin_amdgcn_mfma_f32_16x16x32_f16(pa0, vb0, acc[jd], 0, 0, 0);
      acc[jd] = __builtin_amdgcn_mfma_f32_16x16x32_f16(pa1, vb1, acc[jd], 0, 0, 0);
    }
  }
  const float osc = pscale * sv2;
  #pragma unroll
  for (int jd = 0; jd < 4; ++jd)
    #pragma unroll
    for (int rg = 0; rg < 4; ++rg) {
      int row = l0 + wave * 16 + fq * 4 + rg;
      size_t cidx = ((size_t)(b * LL + row)) * DD + h * HDD + jd * 16 + fr;
      ch[cidx] = f2h(acc[jd][rg] * osc);
    }
}

extern "C" void kernel_launch(void* const* d_in, const int* in_sizes, int n_in,
                              void* d_out, int out_size, void* d_ws, size_t ws_size,
                              hipStream_t stream) {
  const float* x    = (const float*)d_in[0];
  const float* ln1g = (const float*)d_in[1];
  const float* ln1b = (const float*)d_in[2];
  const float* wq   = (const float*)d_in[3];
  const float* bq   = (const float*)d_in[4];
  const float* wk   = (const float*)d_in[5];
  const float* bk   = (const float*)d_in[6];
  const float* wv   = (const float*)d_in[7];
  const float* bv   = (const float*)d_in[8];
  const float* wo   = (const float*)d_in[9];
  const float* bo   = (const float*)d_in[10];
  const float* ln2g = (const float*)d_in[11];
  const float* ln2b = (const float*)d_in[12];
  const float* wfc  = (const float*)d_in[13];
  const float* bfc  = (const float*)d_in[14];
  const float* wpj  = (const float*)d_in[15];
  const float* bpj  = (const float*)d_in[16];
  float* out = (float*)d_out;
  float* ws = (float*)d_ws;

  size_t off = 0;
  float* scal = ws + off; off += 256;
  float* bcat = ws + off; off += 3072;
  unsigned short* wcatQ = (unsigned short*)(ws + off); off += (size_t)3072*DD/2;   // q,k,v stacked
  unsigned short* woQ   = (unsigned short*)(ws + off); off += (size_t)DD*DD/2;
  unsigned short* wfcQ  = (unsigned short*)(ws + off); off += (size_t)FFD*DD/2;
  unsigned short* wpjQ  = (unsigned short*)(ws + off); off += (size_t)DD*FFD/2;
  unsigned short* ah16  = (unsigned short*)(ws + off); off += (size_t)MTOK*DD/2;   // h1 -> ctx -> h2 (fp16)
  float* qkvb = ws + off; off += (size_t)MTOK*3072;   // raw qkv; later opart[2]; later gelf
  float* x1rg = ws + off; off += (size_t)MTOK*DD;     // first qcod+kcod; later x1
  unsigned short* vtc = (unsigned short*)(ws + off); off += (size_t)MTOK*DD/2;
  float* rowm = ws + off; off += (size_t)BB*HH*LL;
  float* rowz = ws + off; off += (size_t)BB*HH*LL;
  float* fcb  = ws + off; off += (size_t)MTOK*FFD;    // fc raw; later pjpart[2]

  unsigned short* qcod = (unsigned short*)x1rg;
  unsigned short* kcod = (unsigned short*)(x1rg + (size_t)MTOK*DD/2);
  float* x1 = x1rg;
  float* opart = qkvb;                        // 2 x [4096x1024]
  unsigned short* gelf = (unsigned short*)qkvb;  // fp16 gelu output [4096x4096]
  float* pjpart = fcb;                        // 2 x [4096x1024]

  const int ND  = MTOK*DD/4;
  const int NF  = MTOK*FFD/4;
  const int NW  = DD*DD/4;
  const int NWF = DD*FFD/4;
  const size_t PS4 = (size_t)MTOK*DD/4;       // part stride in float4s

  auto g4 = [](int n4){ int g = (n4 + 255) / 256; return g > 4096 ? 4096 : g; };

  k_init_bcat<<<12, 256, 0, stream>>>(scal, bq, bk, bv, bcat);

  WSet wset;
  wset.w[0] = wq;  wset.q[0] = wcatQ;                   wset.n4[0] = NW;
  wset.w[1] = wk;  wset.q[1] = wcatQ + (size_t)DD*DD;   wset.n4[1] = NW;
  wset.w[2] = wv;  wset.q[2] = wcatQ + (size_t)2*DD*DD; wset.n4[2] = NW;
  wset.w[3] = wo;  wset.q[3] = woQ;                     wset.n4[3] = NW;
  wset.w[4] = wfc; wset.q[4] = wfcQ;                    wset.n4[4] = NWF;
  wset.w[5] = wpj; wset.q[5] = wpjQ;                    wset.n4[5] = NWF;

  k_absmax6<<<dim3(512, 6), 256, 0, stream>>>(wset, scal);
  k_quantw6<<<dim3(512, 6), 256, 0, stream>>>(wset, scal);

  k_ln_h<<<MTOK, 256, 0, stream>>>(x, ln1g, ln1b, ah16);

  // fused q,k,v GEMM (wide): rows on x, 12 col-tiles of 256; obs pairs at scal+6
  k_gemm_wide<<<dim3(32, 12, 1), 256, 0, stream>>>(ah16, wcatQ, bcat, scal+0, scal+6,
                                                   qkvb, 3072, DD, DD, 10, 0);

  k_quant_codes<<<g4(ND), 256, 0, stream>>>(qkvb, 0,    qcod, scal+6);
  k_quant_codes<<<g4(ND), 256, 0, stream>>>(qkvb, 1024, kcod, scal+8);
  k_quant_codes_vt<<<dim3(8, 16, 8), 256, 0, stream>>>(qkvb, vtc, scal+10);

  k_attn_a_mfma<<<dim3(8, 16, 8), 256, 0, stream>>>(qcod, kcod, scal+6, scal+8,
                                                    rowm, rowz, scal+18);
  k_attn_b_mfma<<<dim3(8, 16, 8), 256, 0, stream>>>(qcod, kcod, vtc, scal+6, scal+8, scal+10,
                                                    rowm, rowz, scal+18, ah16);

  // o GEMM split-K x2 (narrow)
  k_gemm_h<<<dim3(32, 8, 2), 256, 0, stream>>>(ah16, woQ, nullptr, scal+3, nullptr,
                                               opart, DD, DD, 512, 20, (size_t)MTOK*DD);
  k_sum_minmax<<<2048, 256, 0, stream>>>(opart, PS4, 2, bo, ND, 255, scal+19);
  // fused residual + LN2 -> x1 + h2 fp16
  k_res_ln<<<MTOK, 256, 0, stream>>>(opart, PS4, bo, x, x1, scal+19,
                                     ln2g, ln2b, ah16);

  // fc GEMM (wide): N=4096, fused bias+obs
  k_gemm_wide<<<dim3(32, 16, 1), 256, 0, stream>>>(ah16, wfcQ, bfc, scal+4, scal+21,
                                                   fcb, FFD, DD, DD, 20, 0);
  k_gelu_h<<<g4(NF), 256, 0, stream>>>(fcb, gelf, NF, scal+21);

  // pj GEMM (wide) split-K x2 over K=4096
  k_gemm_wide<<<dim3(32, 4, 2), 256, 0, stream>>>(gelf, wpjQ, nullptr, scal+5, nullptr,
                                                  pjpart, DD, FFD, 2048, 20, (size_t)MTOK*DD);
  k_sum_minmax<<<2048, 256, 0, stream>>>(pjpart, PS4, 2, bpj, ND, 255, scal+23);
  k_quant_res2<<<g4(ND), 256, 0, stream>>>(pjpart, PS4, 2, bpj, x1, out, ND, 255, scal+23);
}